// Round 5
// baseline (207.473 us; speedup 1.0000x reference)
//
#include <hip/hip_runtime.h>
#include <hip/hip_bf16.h>
#include <math.h>

#define B 4096
#define NF 50
#define BN_EPS 1e-3f
#define ROWS 16

typedef float f32x4 __attribute__((ext_vector_type(4)));
typedef __bf16 bf16x8 __attribute__((ext_vector_type(8)));
#define MFMA __builtin_amdgcn_mfma_f32_16x16x32_bf16

__device__ __forceinline__ unsigned short f2b(float x) {
  unsigned u = __float_as_uint(x);
  return (unsigned short)((u + 0x7FFFu + ((u >> 16) & 1u)) >> 16);  // RNE
}
__device__ __forceinline__ unsigned packbf(float a, float b) {
  return ((unsigned)f2b(b) << 16) | (unsigned)f2b(a);
}
__device__ __forceinline__ float bs2f(unsigned short u) {
  return __uint_as_float(((unsigned)u) << 16);
}

// ---- workspace layout (unsigned short elements), all n-major for B-frags ----
#define WS_LS  0        // lsb [64][3200]
#define WS_QW  204800   // qwb [64][4096]
#define WS_W0  466944   // w0t [512][192]
#define WS_W1  565248   // w1t [256][512]
#define WS_W2  696320   // w2t [128][256]

// ===========================================================================
// prep: fp32 -> bf16 (+ transpose for W), 8 elements per thread
__global__ __launch_bounds__(256) void prep(
    const float* __restrict__ ls, const float* __restrict__ qw,
    const float* __restrict__ W0, const float* __restrict__ W1,
    const float* __restrict__ W2, unsigned short* __restrict__ ws)
{
  int tid = blockIdx.x * 256 + threadIdx.x;
  if (tid < 25600) {                       // ls: 204800 elems
    int o = tid * 8;
    float4 a = *(const float4*)(ls + o), b = *(const float4*)(ls + o + 4);
    int4 v = {(int)packbf(a.x, a.y), (int)packbf(a.z, a.w),
              (int)packbf(b.x, b.y), (int)packbf(b.z, b.w)};
    *(int4*)&ws[WS_LS + o] = v; return;
  }
  tid -= 25600;
  if (tid < 32768) {                       // qw: 262144 elems
    int o = tid * 8;
    float4 a = *(const float4*)(qw + o), b = *(const float4*)(qw + o + 4);
    int4 v = {(int)packbf(a.x, a.y), (int)packbf(a.z, a.w),
              (int)packbf(b.x, b.y), (int)packbf(b.z, b.w)};
    *(int4*)&ws[WS_QW + o] = v; return;
  }
  tid -= 32768;
  if (tid < 12288) {                       // w0t[n][k] = W0[k][n], 512x192
    int n = tid / 24, k0 = (tid - n * 24) * 8;
    float f[8];
#pragma unroll
    for (int j = 0; j < 8; ++j) f[j] = W0[(k0 + j) * 512 + n];
    int4 v = {(int)packbf(f[0], f[1]), (int)packbf(f[2], f[3]),
              (int)packbf(f[4], f[5]), (int)packbf(f[6], f[7])};
    *(int4*)&ws[WS_W0 + n * 192 + k0] = v; return;
  }
  tid -= 12288;
  if (tid < 16384) {                       // w1t[n][k] = W1[k][n], 256x512
    int n = tid >> 6, k0 = (tid & 63) * 8;
    float f[8];
#pragma unroll
    for (int j = 0; j < 8; ++j) f[j] = W1[(k0 + j) * 256 + n];
    int4 v = {(int)packbf(f[0], f[1]), (int)packbf(f[2], f[3]),
              (int)packbf(f[4], f[5]), (int)packbf(f[6], f[7])};
    *(int4*)&ws[WS_W1 + n * 512 + k0] = v; return;
  }
  tid -= 16384;
  if (tid < 4096) {                        // w2t[n][k] = W2[k][n], 128x256
    int n = tid >> 5, k0 = (tid & 31) * 8;
    float f[8];
#pragma unroll
    for (int j = 0; j < 8; ++j) f[j] = W2[(k0 + j) * 128 + n];
    int4 v = {(int)packbf(f[0], f[1]), (int)packbf(f[2], f[3]),
              (int)packbf(f[4], f[5]), (int)packbf(f[6], f[7])};
    *(int4*)&ws[WS_W2 + n * 256 + k0] = v;
  }
}

// ===========================================================================
__global__ __launch_bounds__(512, 4) void pnn_main(
    const float* __restrict__ fv, const int* __restrict__ idx,
    const float* __restrict__ emb, const float* __restrict__ theta,
    const unsigned short* __restrict__ ws,
    const float* __restrict__ b0p, const float* __restrict__ g0p,
    const float* __restrict__ be0p, const float* __restrict__ m0p,
    const float* __restrict__ v0p,
    const float* __restrict__ b1p, const float* __restrict__ g1p,
    const float* __restrict__ be1p, const float* __restrict__ m1p,
    const float* __restrict__ v1p,
    const float* __restrict__ b2p, const float* __restrict__ g2p,
    const float* __restrict__ be2p, const float* __restrict__ m2p,
    const float* __restrict__ v2p,
    const float* __restrict__ Wout, const float* __restrict__ boutp,
    float* __restrict__ out)
{
  __shared__ int   idx_s[ROWS * NF];
  __shared__ float fv_s[ROWS * NF];
  __shared__ float s_s[ROWS * 64];
  __shared__ float sq_s[ROWS * 64];
  __shared__ float red_s[4 * 256];
  __shared__ unsigned short x_s[ROWS * 200];    // [16][192+8]
  __shared__ unsigned short h0_s[ROWS * 520];   // [16][512+8]
  __shared__ unsigned short h1_s[ROWS * 264];   // [16][256+8]
  __shared__ unsigned short h2_s[ROWS * 136];   // [16][128+8]
  __shared__ unsigned short fbuf[2 * 2 * ROWS * 136];  // dbuf x K-half x [16][136]

  const unsigned short* lsb = ws + WS_LS;
  const unsigned short* qwb = ws + WS_QW;
  const unsigned short* w0t = ws + WS_W0;
  const unsigned short* w1t = ws + WS_W1;
  const unsigned short* w2t = ws + WS_W2;

  const int t  = threadIdx.x;
  const int w  = t >> 6;        // wave 0..7
  const int l  = t & 63;
  const int m16 = l & 15;
  const int qoff = (l >> 4) * 8;
  const int b0 = blockIdx.x * ROWS;
  const int bq = t >> 5;        // staging row 0..15
  const int i2 = (t & 31) * 2;  // staging col pair
  const int kh = w >> 2;        // K-half
  const int d0 = (w & 3) * 16;  // d-tile

  // ---------------- phase 0 ----------------
  for (int i = t; i < ROWS * NF; i += 512) {
    idx_s[i] = idx[b0 * NF + i];
    fv_s[i]  = fv[b0 * NF + i];
  }
  __syncthreads();

  // ---------------- phase 1: l_z (K=3200), s, sq ----------------
  float s0 = 0.f, s1 = 0.f;
  f32x4 az0 = {0.f, 0.f, 0.f, 0.f}, az1 = {0.f, 0.f, 0.f, 0.f};

  for (int c = 0; c < 13; ++c) {
    unsigned short* fb = fbuf + (c & 1) * 4352;
#pragma unroll
    for (int h = 0; h < 4; ++h) {
      int n = 4 * c + h;
      if (n < NF) {
        int iv = idx_s[bq * NF + n];
        float fvv = fv_s[bq * NF + n];
        float2 e = *(const float2*)(emb + (size_t)iv * 64 + i2);
        float p0 = fvv * e.x, p1 = fvv * e.y;
        *(unsigned*)&fb[(h >> 1) * 2176 + bq * 136 + (h & 1) * 64 + i2] = packbf(p0, p1);
        s0 += p0; s1 += p1;
        float q = p0 * p0 + p1 * p1;
        q += __shfl_xor(q, 16); q += __shfl_xor(q, 8); q += __shfl_xor(q, 4);
        q += __shfl_xor(q, 2);  q += __shfl_xor(q, 1);
        if ((t & 31) == 0) sq_s[bq * 64 + n] = q;
      }
    }
    __syncthreads();
    if (!(kh == 1 && c == 12)) {
      const unsigned short* fa = fb + kh * 2176;
      const unsigned short* lp = lsb + (d0 + m16) * 3200 + 256 * c + kh * 128 + qoff;
      int ar = m16 * 136 + qoff;
      bf16x8 bv0 = *(const bf16x8*)(lp);
      bf16x8 bv1 = *(const bf16x8*)(lp + 32);
      bf16x8 bv2 = *(const bf16x8*)(lp + 64);
      bf16x8 bv3 = *(const bf16x8*)(lp + 96);
      bf16x8 a0 = *(const bf16x8*)&fa[ar];
      bf16x8 a1 = *(const bf16x8*)&fa[ar + 32];
      bf16x8 a2 = *(const bf16x8*)&fa[ar + 64];
      bf16x8 a3 = *(const bf16x8*)&fa[ar + 96];
      az0 = MFMA(a0, bv0, az0, 0, 0, 0);
      az1 = MFMA(a1, bv1, az1, 0, 0, 0);
      az0 = MFMA(a2, bv2, az0, 0, 0, 0);
      az1 = MFMA(a3, bv3, az1, 0, 0, 0);
    }
  }
  { float2 sv; sv.x = s0; sv.y = s1; *(float2*)&s_s[bq * 64 + i2] = sv; }
  __syncthreads();

  // reduce l_z across K-halves -> x[:,0:64); l_p_in -> x[:,64:128)
  {
    f32x4 cz;
#pragma unroll
    for (int r = 0; r < 4; ++r) cz[r] = az0[r] + az1[r];
    if (w >= 4) {
      int base = (w - 4) * 256;
#pragma unroll
      for (int r = 0; r < 4; ++r)
        red_s[base + ((l >> 4) * 4 + r) * 16 + m16] = cz[r];
    }
    __syncthreads();
    if (w < 4) {
      int base = w * 256;
#pragma unroll
      for (int r = 0; r < 4; ++r) {
        float v = cz[r] + red_s[base + ((l >> 4) * 4 + r) * 16 + m16];
        x_s[((l >> 4) * 4 + r) * 200 + w * 16 + m16] = f2b(v);
      }
    }
    int d = t & 63, g = t >> 6;
#pragma unroll
    for (int e = 0; e < 2; ++e) {
      int bb = g + 8 * e;
      float a = 0.f;
      for (int n = 0; n < NF; ++n) {
        float th = theta[d * NF + n];
        a += sq_s[bb * 64 + n] * (th * th);
      }
      x_s[bb * 200 + 64 + d] = f2b(a);
    }
  }
  __syncthreads();

  // ---------------- phase 2: l_p_out (K=4096) ----------------
  {
    f32x4 ap0 = {0.f, 0.f, 0.f, 0.f}, ap1 = {0.f, 0.f, 0.f, 0.f};
    for (int c = 0; c < 16; ++c) {
      unsigned short* fb = fbuf + (c & 1) * 4352;
#pragma unroll
      for (int h = 0; h < 4; ++h) {
        int mq = 4 * c + h;
        float pm = s_s[bq * 64 + mq];
        float p0 = pm * s_s[bq * 64 + i2];
        float p1 = pm * s_s[bq * 64 + i2 + 1];
        *(unsigned*)&fb[(h >> 1) * 2176 + bq * 136 + (h & 1) * 64 + i2] = packbf(p0, p1);
      }
      __syncthreads();
      {
        const unsigned short* fa = fb + kh * 2176;
        const unsigned short* qp = qwb + (d0 + m16) * 4096 + 256 * c + kh * 128 + qoff;
        int ar = m16 * 136 + qoff;
        bf16x8 bv0 = *(const bf16x8*)(qp);
        bf16x8 bv1 = *(const bf16x8*)(qp + 32);
        bf16x8 bv2 = *(const bf16x8*)(qp + 64);
        bf16x8 bv3 = *(const bf16x8*)(qp + 96);
        bf16x8 a0 = *(const bf16x8*)&fa[ar];
        bf16x8 a1 = *(const bf16x8*)&fa[ar + 32];
        bf16x8 a2 = *(const bf16x8*)&fa[ar + 64];
        bf16x8 a3 = *(const bf16x8*)&fa[ar + 96];
        ap0 = MFMA(a0, bv0, ap0, 0, 0, 0);
        ap1 = MFMA(a1, bv1, ap1, 0, 0, 0);
        ap0 = MFMA(a2, bv2, ap0, 0, 0, 0);
        ap1 = MFMA(a3, bv3, ap1, 0, 0, 0);
      }
    }
    f32x4 cp;
#pragma unroll
    for (int r = 0; r < 4; ++r) cp[r] = ap0[r] + ap1[r];
    __syncthreads();   // phase-1 red_s reads done (already sync'd); reuse red_s
    if (w >= 4) {
      int base = (w - 4) * 256;
#pragma unroll
      for (int r = 0; r < 4; ++r)
        red_s[base + ((l >> 4) * 4 + r) * 16 + m16] = cp[r];
    }
    __syncthreads();
    if (w < 4) {
      int base = w * 256;
#pragma unroll
      for (int r = 0; r < 4; ++r) {
        float v = cp[r] + red_s[base + ((l >> 4) * 4 + r) * 16 + m16];
        x_s[((l >> 4) * 4 + r) * 200 + 128 + w * 16 + m16] = f2b(v);
      }
    }
  }
  __syncthreads();

  // ---------------- phase 3: MLP, B-frags straight from global ----------------
  // layer 0: 192 -> 512
  {
    int ar = m16 * 200 + qoff;
    bf16x8 xa[6];
#pragma unroll
    for (int kc = 0; kc < 6; ++kc) xa[kc] = *(const bf16x8*)&x_s[ar + kc * 32];
    for (int j = 0; j < 4; ++j) {
      int n0 = (w * 4 + j) * 16;
      const unsigned short* wp = w0t + (n0 + m16) * 192 + qoff;
      f32x4 ha = {0.f, 0.f, 0.f, 0.f}, hb = {0.f, 0.f, 0.f, 0.f};
#pragma unroll
      for (int kc = 0; kc < 6; ++kc) {
        bf16x8 bv = *(const bf16x8*)(wp + kc * 32);
        if (kc & 1) hb = MFMA(xa[kc], bv, hb, 0, 0, 0);
        else        ha = MFMA(xa[kc], bv, ha, 0, 0, 0);
      }
      int n = n0 + m16;
      float sc = g0p[n] * rsqrtf(v0p[n] + BN_EPS);
      float sh = be0p[n] + (b0p[n] - m0p[n]) * sc;
#pragma unroll
      for (int r = 0; r < 4; ++r) {
        float v = fmaxf((ha[r] + hb[r]) * sc + sh, 0.f);
        h0_s[((l >> 4) * 4 + r) * 520 + n] = f2b(v);
      }
    }
  }
  __syncthreads();

  // layer 1: 512 -> 256
  for (int j = 0; j < 2; ++j) {
    int n0 = (w * 2 + j) * 16;
    const unsigned short* wp = w1t + (n0 + m16) * 512 + qoff;
    int ar = m16 * 520 + qoff;
    f32x4 ha = {0.f, 0.f, 0.f, 0.f}, hb = {0.f, 0.f, 0.f, 0.f};
#pragma unroll
    for (int kc = 0; kc < 16; ++kc) {
      bf16x8 av = *(const bf16x8*)&h0_s[ar + kc * 32];
      bf16x8 bv = *(const bf16x8*)(wp + kc * 32);
      if (kc & 1) hb = MFMA(av, bv, hb, 0, 0, 0);
      else        ha = MFMA(av, bv, ha, 0, 0, 0);
    }
    int n = n0 + m16;
    float sc = g1p[n] * rsqrtf(v1p[n] + BN_EPS);
    float sh = be1p[n] + (b1p[n] - m1p[n]) * sc;
#pragma unroll
    for (int r = 0; r < 4; ++r) {
      float v = fmaxf((ha[r] + hb[r]) * sc + sh, 0.f);
      h1_s[((l >> 4) * 4 + r) * 264 + n] = f2b(v);
    }
  }
  __syncthreads();

  // layer 2: 256 -> 128
  {
    int n0 = w * 16;
    const unsigned short* wp = w2t + (n0 + m16) * 256 + qoff;
    int ar = m16 * 264 + qoff;
    f32x4 ha = {0.f, 0.f, 0.f, 0.f}, hb = {0.f, 0.f, 0.f, 0.f};
#pragma unroll
    for (int kc = 0; kc < 8; ++kc) {
      bf16x8 av = *(const bf16x8*)&h1_s[ar + kc * 32];
      bf16x8 bv = *(const bf16x8*)(wp + kc * 32);
      if (kc & 1) hb = MFMA(av, bv, hb, 0, 0, 0);
      else        ha = MFMA(av, bv, ha, 0, 0, 0);
    }
    int n = n0 + m16;
    float sc = g2p[n] * rsqrtf(v2p[n] + BN_EPS);
    float sh = be2p[n] + (b2p[n] - m2p[n]) * sc;
#pragma unroll
    for (int r = 0; r < 4; ++r) {
      float v = fmaxf((ha[r] + hb[r]) * sc + sh, 0.f);
      h2_s[((l >> 4) * 4 + r) * 136 + n] = f2b(v);
    }
  }
  __syncthreads();

  // output: sigmoid(h2 @ Wout + bout)
  if (t < 128) {
    int bb = t >> 3, seg = t & 7;
    float a = 0.f;
#pragma unroll
    for (int j = 0; j < 16; ++j) {
      int k = seg * 16 + j;
      a += bs2f(h2_s[bb * 136 + k]) * Wout[k];
    }
    a += __shfl_xor(a, 4); a += __shfl_xor(a, 2); a += __shfl_xor(a, 1);
    if (seg == 0) out[b0 + bb] = 1.f / (1.f + expf(-(a + boutp[0])));
  }
}

// ===========================================================================
extern "C" void kernel_launch(void* const* d_in, const int* in_sizes, int n_in,
                              void* d_out, int out_size, void* d_ws, size_t ws_size,
                              hipStream_t stream)
{
  (void)in_sizes; (void)n_in; (void)out_size; (void)ws_size;
  unsigned short* ws = (unsigned short*)d_ws;

  prep<<<356, 256, 0, stream>>>(
      (const float*)d_in[3], (const float*)d_in[5], (const float*)d_in[6],
      (const float*)d_in[12], (const float*)d_in[18], ws);

  pnn_main<<<B / ROWS, 512, 0, stream>>>(
      (const float*)d_in[0], (const int*)d_in[1], (const float*)d_in[2],
      (const float*)d_in[4], ws,
      (const float*)d_in[7],  (const float*)d_in[8],  (const float*)d_in[9],
      (const float*)d_in[10], (const float*)d_in[11],
      (const float*)d_in[13], (const float*)d_in[14], (const float*)d_in[15],
      (const float*)d_in[16], (const float*)d_in[17],
      (const float*)d_in[19], (const float*)d_in[20], (const float*)d_in[21],
      (const float*)d_in[22], (const float*)d_in[23],
      (const float*)d_in[24], (const float*)d_in[25],
      (float*)d_out);
}